// Round 23
// baseline (106.382 us; speedup 1.0000x reference)
//
#include <hip/hip_runtime.h>
#include <hip/hip_bf16.h>
#include <stdint.h>

#define NB 16
#define NS 1024
#define ND 512
#define NO 512
#define NROW (NB*NS)   // 16384
#define SIM_BAND 1.5e-3f

typedef float f32x4 __attribute__((ext_vector_type(4)));
typedef _Float16 f16x8 __attribute__((ext_vector_type(8)));

// ---------------- K1: merged W-prep: blocks 0..31 = Wf frag tiles (f16), 32..33 = watt ----------------
__global__ __launch_bounds__(256) void k_prep_w2(const float* __restrict__ W,
                                                 const float* __restrict__ att_src,
                                                 const float* __restrict__ att_dst,
                                                 _Float16* __restrict__ Wf,
                                                 float* __restrict__ watt_s,
                                                 float* __restrict__ watt_d) {
  __shared__ float as_[512], ad_[512];
  int blk = blockIdx.x, tid = threadIdx.x;
  if (blk < 32) {
    int mt = blk>>3, k0c = blk&7;
    size_t base = ((size_t)(mt*8 + k0c))*8192;
    #pragma unroll
    for (int pp = 0; pp < 4; ++pp) {
      int id = pp*256 + tid;
      int kb = id>>9, m = (id>>6)&7, g = (id>>4)&3, r = id&15;
      int o = mt*128 + m*16 + r;
      int d0 = k0c*64 + kb*32 + g*8;
      union { _Float16 h[8]; uint4 u; } pk;
      #pragma unroll
      for (int j = 0; j < 8; ++j) pk.h[j] = (_Float16)W[(size_t)(d0+j)*NO + o];
      *(uint4*)&Wf[base + id*8] = pk.u;
    }
  } else {
    as_[tid] = att_src[tid]; as_[tid+256] = att_src[tid+256];
    ad_[tid] = att_dst[tid]; ad_[tid+256] = att_dst[tid+256];
    __syncthreads();
    int d = (blk-32)*256 + tid;
    const float* wr = W + (size_t)d*NO;
    float s = 0.f, dd = 0.f;
    for (int o = 0; o < NO; o += 4) {
      float4 w = *(const float4*)&wr[o];
      s  = fmaf(w.x, as_[o], fmaf(w.y, as_[o+1], fmaf(w.z, as_[o+2], fmaf(w.w, as_[o+3], s))));
      dd = fmaf(w.x, ad_[o], fmaf(w.y, ad_[o+1], fmaf(w.z, ad_[o+2], fmaf(w.w, ad_[o+3], dd))));
    }
    watt_s[d] = s;
    watt_d[d] = dd;
  }
}

// ---------------- K2: rnorm + a_src/a_dst (via watt) + yf = f16(x*rn) fragment-order ----------------
__global__ __launch_bounds__(256) void k_prep_y(const float* __restrict__ x,
                                                _Float16* __restrict__ yf,
                                                float* __restrict__ rnorm,
                                                float* __restrict__ a_src,
                                                float* __restrict__ a_dst,
                                                const float* __restrict__ watt_s,
                                                const float* __restrict__ watt_d) {
  __shared__ float ws_[512], wd_[512];
  int tid = threadIdx.x, blk = blockIdx.x;
  ws_[tid] = watt_s[tid]; ws_[tid+256] = watt_s[tid+256];
  wd_[tid] = watt_d[tid]; wd_[tid+256] = watt_d[tid+256];
  __syncthreads();
  int r = tid>>2, q = tid&3;
  int grow = blk*64 + r;
  const float* xr = x + (size_t)grow*ND + q*128;
  float ssq = 0.f, as = 0.f, ad = 0.f;
  #pragma unroll
  for (int c8 = 0; c8 < 16; ++c8) {
    float4 v0 = *(const float4*)&xr[c8*8];
    float4 v1 = *(const float4*)&xr[c8*8+4];
    float vv[8] = {v0.x,v0.y,v0.z,v0.w,v1.x,v1.y,v1.z,v1.w};
    #pragma unroll
    for (int j = 0; j < 8; ++j) {
      int c = q*128 + c8*8 + j;
      ssq = fmaf(vv[j], vv[j], ssq);
      as  = fmaf(vv[j], ws_[c], as);
      ad  = fmaf(vv[j], wd_[c], ad);
    }
  }
  ssq += __shfl_xor(ssq, 1, 64); ssq += __shfl_xor(ssq, 2, 64);
  as  += __shfl_xor(as, 1, 64);  as  += __shfl_xor(as, 2, 64);
  ad  += __shfl_xor(ad, 1, 64);  ad  += __shfl_xor(ad, 2, 64);
  float rn = 1.0f / fmaxf(sqrtf(ssq), 1e-12f);
  if (q == 0) { rnorm[grow] = rn; a_src[grow] = as; a_dst[grow] = ad; }
  int trow = grow & (NS-1), b = grow >> 10;
  int m = (trow>>4)&7, rr = trow&15;
  size_t tilebase = ((size_t)(b*8 + (trow>>7)))*65536;
  #pragma unroll
  for (int c8 = 0; c8 < 16; ++c8) {
    int col = q*128 + c8*8;
    int k0c = col>>6, cc = col&63, kb = cc>>5, g = (cc>>3)&3;
    int id = kb*512 + m*64 + g*16 + rr;
    size_t off = tilebase + (size_t)k0c*8192 + id*8;
    float4 v0 = *(const float4*)&xr[c8*8];
    float4 v1 = *(const float4*)&xr[c8*8+4];
    float vv[8] = {v0.x,v0.y,v0.z,v0.w,v1.x,v1.y,v1.z,v1.w};
    union { _Float16 h[8]; uint4 u; } pk;
    #pragma unroll
    for (int j = 0; j < 8; ++j) pk.h[j] = (_Float16)(vv[j]*rn);   // RTN f16
    *(uint4*)&yf[off] = pk.u;
  }
}

// ---- zero-LDS fragment load (half h covers 32 k-cols): frag = base + h*4096 + q*512 ----
#define FRAG_LD(AH, BH, APTR, BPTR, h) do { \
    _Pragma("unroll") \
    for (int q_ = 0; q_ < 4; ++q_) { \
      AH[q_] = *(const f16x8*)&APTR[Abase + (size_t)(h)*4096 + (size_t)(aq + q_)*512]; \
      BH[q_] = *(const f16x8*)&BPTR[Bbase + (size_t)(h)*4096 + (size_t)(bq + q_)*512]; \
    } \
  } while(0)

#define MFMA16(AH, BH) do { \
    _Pragma("unroll") \
    for (int mi_ = 0; mi_ < 4; ++mi_) \
      _Pragma("unroll") \
      for (int ni_ = 0; ni_ < 4; ++ni_) \
        acc[mi_][ni_] = __builtin_amdgcn_mfma_f32_16x16x32_f16(AH[mi_], BH[ni_], acc[mi_][ni_], 0,0,0); \
  } while(0)

// 4-deep register pipeline over 16 halves (4 iterations x 4 sets)
#define PIPE16(APTR, BPTR) do { \
    FRAG_LD(A0, B0, APTR, BPTR, 0); \
    FRAG_LD(A1, B1, APTR, BPTR, 1); \
    FRAG_LD(A2, B2, APTR, BPTR, 2); \
    for (int it = 0; it < 4; ++it) { \
      FRAG_LD(A3, B3, APTR, BPTR, 4*it+3); \
      MFMA16(A0, B0); \
      if (it < 3) FRAG_LD(A0, B0, APTR, BPTR, 4*it+4); \
      MFMA16(A1, B1); \
      if (it < 3) FRAG_LD(A1, B1, APTR, BPTR, 4*it+5); \
      MFMA16(A2, B2); \
      if (it < 3) FRAG_LD(A2, B2, APTR, BPTR, 4*it+6); \
      MFMA16(A3, B3); \
    } \
  } while(0)

// ---------------- K3 (fused): blocks 0..575 = sim -> Mbits+Bbits; 576..1087 = gemm_ht ----------------
// __launch_bounds__(256, 2): VGPR cap 256 so the 4-deep pipeline's sets all stay live.
__global__ __launch_bounds__(256, 2) void k_sim_ht(const _Float16* __restrict__ yf,
                                                   const _Float16* __restrict__ Wf,
                                                   const float* __restrict__ rnorm,
                                                   uint16_t* __restrict__ Mbits,
                                                   uint16_t* __restrict__ Bbits,
                                                   _Float16* __restrict__ htf) {
  __shared__ __align__(16) _Float16 sbuf[16384];   // used only by ht path (output staging)
  int bid0 = blockIdx.x;
  int tid = threadIdx.x, wid = tid>>6, lane = tid&63;
  int wm = (wid>>1)*64, wn = (wid&1)*64;
  int aq = (wm>>4), bq = (wn>>4);
  if (bid0 < 576) {
    // ---- sim path: zero-LDS, 4-deep register pipeline ----
    int swz = (bid0 & 7)*72 + (bid0 >> 3);      // bijective: 576 = 8*72
    int b = swz / 36, p = swz - b*36;
    int ti = 0;
    while ((ti+1)*(ti+2)/2 <= p) ++ti;
    int tj = p - ti*(ti+1)/2;                   // tj <= ti
    size_t Abase = ((size_t)(b*8+ti))*65536 + (size_t)lane*8;
    size_t Bbase = ((size_t)(b*8+tj))*65536 + (size_t)lane*8;
    f32x4 acc[4][4] = {};
    f16x8 A0[4], B0[4], A1[4], B1[4], A2[4], B2[4], A3[4], B3[4];
    PIPE16(yf, yf);
    int hi = lane>>4, colL = lane&15;
    #pragma unroll
    for (int mi = 0; mi < 4; ++mi) {
      #pragma unroll
      for (int r2 = 0; r2 < 4; ++r2) {
        int t_g = ti*128 + wm + mi*16 + hi*4 + r2;
        int git = b*NS + t_g;
        #pragma unroll
        for (int ni = 0; ni < 4; ++ni) {
          int s_g = tj*128 + wn + ni*16 + colL;
          float sim = acc[mi][ni][r2];
          bool bit  = (s_g == t_g) || (s_g < t_g && sim > 0.9f);
          bool cond = (s_g < t_g) && (fabsf(sim - 0.9f) <= SIM_BAND);
          unsigned long long bal = __ballot(bit);
          unsigned long long bb  = __ballot(cond);
          if (colL == 0) {
            int widx = (tj*128 + wn + ni*16)>>4;
            Mbits[(size_t)git*64 + widx] = (uint16_t)((bal >> (hi*16)) & 0xFFFFull);
            Bbits[(size_t)git*64 + widx] = (uint16_t)((bb  >> (hi*16)) & 0xFFFFull);
          }
        }
      }
    }
  } else {
    // ---- gemm_ht path: zero-LDS, 4-deep pipeline; LDS only for coalesced output ----
    int bidh = bid0 - 576;
    int swz = (bidh&7)*64 + (bidh>>3);          // bijective: 512 = 8*64
    int mt = swz&3, it2 = swz>>2;
    int b = it2>>3, tblk = it2&7;
    size_t Abase = ((size_t)mt)*65536 + (size_t)lane*8;
    size_t Bbase = ((size_t)(b*8+tblk))*65536 + (size_t)lane*8;
    f32x4 acc[4][4] = {};
    f16x8 A0[4], B0[4], A1[4], B1[4], A2[4], B2[4], A3[4], B3[4];
    PIPE16(Wf, yf);
    {
      int rbase = (lane>>4)*4, colL = lane&15;
      #pragma unroll
      for (int ni = 0; ni < 4; ++ni) {
        int i_local = wn + ni*16 + colL;
        int gn = it2*128 + i_local;
        float xn = 1.0f / rnorm[gn];
        int tsel = i_local>>6, ic = i_local&63;
        int kb = ic>>5, g = (ic>>3)&3, j = ic&7;
        int base = tsel*8192 + (kb*512 + g*16)*8 + j;
        #pragma unroll
        for (int mi = 0; mi < 4; ++mi)
          #pragma unroll
          for (int r2 = 0; r2 < 4; ++r2) {
            int o_local = wm + mi*16 + rbase + r2;
            int m = o_local>>4, r = o_local&15;
            sbuf[base + (m*64 + r)*8] = (_Float16)(acc[mi][ni][r2] * xn);
          }
      }
    }
    __syncthreads();
    {
      size_t gbase = ((size_t)((mt*NB + b)*16 + tblk*2))*8192;
      const uint4* src = (const uint4*)sbuf;
      uint4* dst = (uint4*)(htf + gbase);
      #pragma unroll
      for (int k = 0; k < 8; ++k) dst[tid + k*256] = src[tid + k*256];
    }
  }
}

// ---------------- K4: masked softmax w/ inline wave-cooperative exact recheck -> Pf ----------------
__global__ __launch_bounds__(256) void k_softmax(const uint32_t* __restrict__ Mw,
                                                 const uint32_t* __restrict__ Bw,
                                                 const float* __restrict__ x,
                                                 const float* __restrict__ rnorm,
                                                 const float* __restrict__ a_src,
                                                 const float* __restrict__ a_dst,
                                                 _Float16* __restrict__ Pf) {
  __shared__ __align__(16) _Float16 pbuf[4][1032];
  int wid = threadIdx.x>>6, lane = threadIdx.x&63;
  int rowid = blockIdx.x*4 + wid;
  int t = rowid & (NS-1), b = rowid >> 10;
  int n = t + 1;
  const float* as = a_src + b*NS;
  float adv = a_dst[rowid];
  uint32_t w = Mw[(size_t)rowid*32 + (lane>>1)];
  uint32_t bits16 = (lane&1) ? (w>>16) : (w & 0xFFFFu);
  uint32_t w2 = Bw[(size_t)rowid*32 + (lane>>1)];
  uint32_t bb16 = (lane&1) ? (w2>>16) : (w2 & 0xFFFFu);
  int s0 = lane*16;
  // CAUSAL GATE: chunks with s >= n were never written by sim (hold ws poison) -> mask them out
  {
    int rem = n - s0;
    uint32_t gmask = (rem <= 0) ? 0u : (rem >= 16 ? 0xFFFFu : ((1u<<rem)-1u));
    bb16 &= gmask;
  }
  float4 a0 = *(const float4*)&as[s0];
  float4 a1 = *(const float4*)&as[s0+4];
  float4 a2 = *(const float4*)&as[s0+8];
  float4 a3 = *(const float4*)&as[s0+12];
  float va[16] = {a0.x,a0.y,a0.z,a0.w, a1.x,a1.y,a1.z,a1.w,
                  a2.x,a2.y,a2.z,a2.w, a3.x,a3.y,a3.z,a3.w};
  float pr[16];
  #pragma unroll
  for (int k = 0; k < 16; ++k) {
    int s = s0 + k;
    bool on = (s < n) && ((bits16>>k)&1);
    float vv = adv + va[k];
    float v = (vv > 0.f) ? vv : 0.2f*vv;
    pr[k] = on ? v : -INFINITY;
  }
  // ---- inline exact recheck (wave-cooperative); decisions collected in bitmasks ----
  uint32_t fix_on = 0u, fix_off = 0u;
  unsigned long long anyb = __ballot(bb16 != 0u);
  if (anyb) {
    float rnt = rnorm[rowid];
    const float* xt = x + (size_t)rowid*ND + lane*8;
    float4 t0v = *(const float4*)xt;
    float4 t1v = *(const float4*)(xt+4);
    while (anyb) {
      int src_lane = __ffsll(anyb) - 1;
      anyb &= anyb - 1ULL;
      unsigned bits = __shfl(bb16, src_lane, 64);
      while (bits) {
        int k = __ffs(bits) - 1;
        bits &= bits - 1u;
        int s = src_lane*16 + k;
        const float* xs = x + ((size_t)(b*NS + s))*ND + lane*8;
        float4 s0v = *(const float4*)xs;
        float4 s1v = *(const float4*)(xs+4);
        float d = 0.f;
        d = fmaf(t0v.x,s0v.x, fmaf(t0v.y,s0v.y, fmaf(t0v.z,s0v.z, fmaf(t0v.w,s0v.w, d))));
        d = fmaf(t1v.x,s1v.x, fmaf(t1v.y,s1v.y, fmaf(t1v.z,s1v.z, fmaf(t1v.w,s1v.w, d))));
        #pragma unroll
        for (int off = 32; off > 0; off >>= 1) d += __shfl_xor(d, off, 64);
        float sim = d * rnt * rnorm[b*NS+s];
        bool on2 = sim > 0.9f;
        if (lane == src_lane) {
          if (on2) fix_on  |= (1u<<k);
          else     fix_off |= (1u<<k);
        }
      }
    }
  }
  #pragma unroll
  for (int k = 0; k < 16; ++k) {
    float vv = adv + va[k];
    float v = (vv > 0.f) ? vv : 0.2f*vv;
    if ((fix_on >>k)&1) pr[k] = v;
    if ((fix_off>>k)&1) pr[k] = -INFINITY;
  }
  // ---- reduction + normalize + frag-order store ----
  float lm = -INFINITY;
  #pragma unroll
  for (int k = 0; k < 16; ++k) lm = fmaxf(lm, pr[k]);
  #pragma unroll
  for (int off = 32; off > 0; off >>= 1) lm = fmaxf(lm, __shfl_xor(lm, off, 64));
  float ls = 0.f;
  #pragma unroll
  for (int k = 0; k < 16; ++k) { pr[k] = __expf(pr[k] - lm); ls += pr[k]; }
  #pragma unroll
  for (int off = 32; off > 0; off >>= 1) ls += __shfl_xor(ls, off, 64);
  float inv = 1.0f / ls;
  union { _Float16 hh[8]; uint4 u; } pk0, pk1;
  #pragma unroll
  for (int j = 0; j < 8; ++j) pk0.hh[j] = (_Float16)(pr[j]*inv);
  #pragma unroll
  for (int j = 0; j < 8; ++j) pk1.hh[j] = (_Float16)(pr[8+j]*inv);
  *(uint4*)&pbuf[wid][s0]   = pk0.u;
  *(uint4*)&pbuf[wid][s0+8] = pk1.u;
  __syncthreads();
  int t0 = (blockIdx.x*4) & (NS-1);
  int b0 = (blockIdx.x*4) >> 10;
  int end = ((t0 >> 7) + 1) << 7;
  int m = (t0>>4)&7, r0 = t0&15;
  size_t tbase = ((size_t)(b0*8 + (t0>>7)))*131072;
  int nslots = (end>>3)*4;
  for (int u = threadIdx.x; u < nslots; u += 256) {
    int rr = u&3, c8 = u>>2;
    int icol = c8*8;
    int k0c = icol>>6, kb = (icol>>5)&1, g = (icol>>3)&3;
    uint4 v = *(const uint4*)&pbuf[rr][icol];
    *(uint4*)&Pf[tbase + (size_t)k0c*8192 + (size_t)(kb*512 + m*64 + g*16 + r0 + rr)*8] = v;
  }
}

// ---------------- K5: out = relu(P @ h + bias) -- zero-LDS, 4-deep pipeline, causal ----------------
__global__ __launch_bounds__(256, 2) void k_pv(const _Float16* __restrict__ Pf,
                                               const _Float16* __restrict__ htf,
                                               const float* __restrict__ bias,
                                               float* __restrict__ out) {
  int bid = blockIdx.x;
  int swz = (bid&7)*64 + (bid>>3);          // bijective: 512 = 8*64
  int b = swz>>5, rem = swz&31, mt = rem>>2, nt = rem&3;
  int tid = threadIdx.x, wid = tid>>6, lane = tid&63;
  int wm = (wid>>1)*64, wn = (wid&1)*64;
  size_t Abase = ((size_t)((b*8 + mt)*16))*8192 + (size_t)lane*8;
  size_t Bbase = ((size_t)((nt*NB + b)*16))*8192 + (size_t)lane*8;
  int aq = (wm>>4), bq = (wn>>4);
  f32x4 acc[4][4] = {};
  f16x8 A0[4], B0[4], A1[4], B1[4], A2[4], B2[4], A3[4], B3[4];
  // 4-deep pipeline over 4*(mt+1) causal halves
  FRAG_LD(A0, B0, Pf, htf, 0);
  FRAG_LD(A1, B1, Pf, htf, 1);
  FRAG_LD(A2, B2, Pf, htf, 2);
  for (int it = 0; it <= mt; ++it) {
    FRAG_LD(A3, B3, Pf, htf, 4*it+3);
    MFMA16(A0, B0);
    if (it < mt) FRAG_LD(A0, B0, Pf, htf, 4*it+4);
    MFMA16(A1, B1);
    if (it < mt) FRAG_LD(A1, B1, Pf, htf, 4*it+5);
    MFMA16(A2, B2);
    if (it < mt) FRAG_LD(A2, B2, Pf, htf, 4*it+6);
    MFMA16(A3, B3);
  }
  int m0 = mt*128, n0 = nt*128;
  int rbase = (lane>>4)*4, col = lane&15;
  #pragma unroll
  for (int mi = 0; mi < 4; ++mi)
    #pragma unroll
    for (int ni = 0; ni < 4; ++ni) {
      int gm = m0 + wm + mi*16 + rbase;
      int gn = n0 + wn + ni*16 + col;
      float bv = bias[gn];
      #pragma unroll
      for (int r2 = 0; r2 < 4; ++r2)
        out[((size_t)b*NS + gm + r2)*NO + gn] = fmaxf(acc[mi][ni][r2] + bv, 0.0f);
    }
}

extern "C" void kernel_launch(void* const* d_in, const int* in_sizes, int n_in,
                              void* d_out, int out_size, void* d_ws, size_t ws_size,
                              hipStream_t stream) {
  (void)in_sizes; (void)n_in; (void)out_size; (void)ws_size;
  const float* x       = (const float*)d_in[0];
  const float* W       = (const float*)d_in[1];
  const float* att_src = (const float*)d_in[2];
  const float* att_dst = (const float*)d_in[3];
  const float* bias    = (const float*)d_in[4];
  float* out = (float*)d_out;

  char* ws = (char*)d_ws;
  _Float16*     yf    = (_Float16*)    (ws + 0);           // 16 MB [prep_y..sim_ht]
  _Float16*     htf   = (_Float16*)    (ws + 16777216);    // 16 MB [sim_ht..pv]
  _Float16*     Pf    = (_Float16*)    (ws + 33554432);    // 32 MB [softmax..pv]
  uint16_t*     Mbits = (uint16_t*)    (ws + 67108864);    //  2 MB [sim_ht..softmax]
  uint16_t*     Bbits = (uint16_t*)    (ws + 69206016);    //  2 MB [sim_ht..softmax]
  _Float16*     Wf    = (_Float16*)    (ws + 71303168);    // 512 KB [prep_w2..sim_ht]
  float*        watt_s= (float*)       (ws + 71827456);    //  2 KB
  float*        watt_d= (float*)       (ws + 71829504);    //  2 KB
  float*        rnorm = (float*)       (ws + 71831552);    // 64 KB
  float*        a_src = (float*)       (ws + 71897088);    // 64 KB
  float*        a_dst = (float*)       (ws + 71962624);    // 64 KB

  k_prep_w2<<<dim3(34),   dim3(256), 0, stream>>>(W, att_src, att_dst, Wf, watt_s, watt_d);
  k_prep_y <<<dim3(256),  dim3(256), 0, stream>>>(x, yf, rnorm, a_src, a_dst, watt_s, watt_d);
  k_sim_ht <<<dim3(1088), dim3(256), 0, stream>>>(yf, Wf, rnorm, Mbits, Bbits, htf);
  k_softmax<<<dim3(4096), dim3(256), 0, stream>>>((const uint32_t*)Mbits, (const uint32_t*)Bbits,
                                                  x, rnorm, a_src, a_dst, Pf);
  k_pv     <<<dim3(512),  dim3(256), 0, stream>>>(Pf, htf, bias, out);
}

// Round 24
// 100.156 us; speedup vs baseline: 1.0622x; 1.0622x over previous
//
#include <hip/hip_runtime.h>
#include <hip/hip_bf16.h>
#include <stdint.h>

#define NB 16
#define NS 1024
#define ND 512
#define NO 512
#define NROW (NB*NS)   // 16384
#define SIM_BAND 1.5e-3f

typedef float f32x4 __attribute__((ext_vector_type(4)));
typedef _Float16 f16x8 __attribute__((ext_vector_type(8)));

// ---------------- K1: merged W-prep: blocks 0..31 = Wf frag tiles (f16), 32..33 = watt ----------------
__global__ __launch_bounds__(256) void k_prep_w2(const float* __restrict__ W,
                                                 const float* __restrict__ att_src,
                                                 const float* __restrict__ att_dst,
                                                 _Float16* __restrict__ Wf,
                                                 float* __restrict__ watt_s,
                                                 float* __restrict__ watt_d) {
  __shared__ float as_[512], ad_[512];
  int blk = blockIdx.x, tid = threadIdx.x;
  if (blk < 32) {
    int mt = blk>>3, k0c = blk&7;
    size_t base = ((size_t)(mt*8 + k0c))*8192;
    #pragma unroll
    for (int pp = 0; pp < 4; ++pp) {
      int id = pp*256 + tid;
      int kb = id>>9, m = (id>>6)&7, g = (id>>4)&3, r = id&15;
      int o = mt*128 + m*16 + r;
      int d0 = k0c*64 + kb*32 + g*8;
      union { _Float16 h[8]; uint4 u; } pk;
      #pragma unroll
      for (int j = 0; j < 8; ++j) pk.h[j] = (_Float16)W[(size_t)(d0+j)*NO + o];
      *(uint4*)&Wf[base + id*8] = pk.u;
    }
  } else {
    as_[tid] = att_src[tid]; as_[tid+256] = att_src[tid+256];
    ad_[tid] = att_dst[tid]; ad_[tid+256] = att_dst[tid+256];
    __syncthreads();
    int d = (blk-32)*256 + tid;
    const float* wr = W + (size_t)d*NO;
    float s = 0.f, dd = 0.f;
    for (int o = 0; o < NO; o += 4) {
      float4 w = *(const float4*)&wr[o];
      s  = fmaf(w.x, as_[o], fmaf(w.y, as_[o+1], fmaf(w.z, as_[o+2], fmaf(w.w, as_[o+3], s))));
      dd = fmaf(w.x, ad_[o], fmaf(w.y, ad_[o+1], fmaf(w.z, ad_[o+2], fmaf(w.w, ad_[o+3], dd))));
    }
    watt_s[d] = s;
    watt_d[d] = dd;
  }
}

// ---------------- K2: rnorm + a_src/a_dst (via watt) + yf = f16(x*rn) fragment-order ----------------
__global__ __launch_bounds__(256) void k_prep_y(const float* __restrict__ x,
                                                _Float16* __restrict__ yf,
                                                float* __restrict__ rnorm,
                                                float* __restrict__ a_src,
                                                float* __restrict__ a_dst,
                                                const float* __restrict__ watt_s,
                                                const float* __restrict__ watt_d) {
  __shared__ float ws_[512], wd_[512];
  int tid = threadIdx.x, blk = blockIdx.x;
  ws_[tid] = watt_s[tid]; ws_[tid+256] = watt_s[tid+256];
  wd_[tid] = watt_d[tid]; wd_[tid+256] = watt_d[tid+256];
  __syncthreads();
  int r = tid>>2, q = tid&3;
  int grow = blk*64 + r;
  const float* xr = x + (size_t)grow*ND + q*128;
  float ssq = 0.f, as = 0.f, ad = 0.f;
  #pragma unroll
  for (int c8 = 0; c8 < 16; ++c8) {
    float4 v0 = *(const float4*)&xr[c8*8];
    float4 v1 = *(const float4*)&xr[c8*8+4];
    float vv[8] = {v0.x,v0.y,v0.z,v0.w,v1.x,v1.y,v1.z,v1.w};
    #pragma unroll
    for (int j = 0; j < 8; ++j) {
      int c = q*128 + c8*8 + j;
      ssq = fmaf(vv[j], vv[j], ssq);
      as  = fmaf(vv[j], ws_[c], as);
      ad  = fmaf(vv[j], wd_[c], ad);
    }
  }
  ssq += __shfl_xor(ssq, 1, 64); ssq += __shfl_xor(ssq, 2, 64);
  as  += __shfl_xor(as, 1, 64);  as  += __shfl_xor(as, 2, 64);
  ad  += __shfl_xor(ad, 1, 64);  ad  += __shfl_xor(ad, 2, 64);
  float rn = 1.0f / fmaxf(sqrtf(ssq), 1e-12f);
  if (q == 0) { rnorm[grow] = rn; a_src[grow] = as; a_dst[grow] = ad; }
  int trow = grow & (NS-1), b = grow >> 10;
  int m = (trow>>4)&7, rr = trow&15;
  size_t tilebase = ((size_t)(b*8 + (trow>>7)))*65536;
  #pragma unroll
  for (int c8 = 0; c8 < 16; ++c8) {
    int col = q*128 + c8*8;
    int k0c = col>>6, cc = col&63, kb = cc>>5, g = (cc>>3)&3;
    int id = kb*512 + m*64 + g*16 + rr;
    size_t off = tilebase + (size_t)k0c*8192 + id*8;
    float4 v0 = *(const float4*)&xr[c8*8];
    float4 v1 = *(const float4*)&xr[c8*8+4];
    float vv[8] = {v0.x,v0.y,v0.z,v0.w,v1.x,v1.y,v1.z,v1.w};
    union { _Float16 h[8]; uint4 u; } pk;
    #pragma unroll
    for (int j = 0; j < 8; ++j) pk.h[j] = (_Float16)(vv[j]*rn);   // RTN f16
    *(uint4*)&yf[off] = pk.u;
  }
}

// ---- zero-LDS fragment load (half h covers 32 k-cols): frag = base + h*4096 + q*512 ----
#define FRAG_LD(AH, BH, APTR, BPTR, h) do { \
    _Pragma("unroll") \
    for (int q_ = 0; q_ < 4; ++q_) { \
      AH[q_] = *(const f16x8*)&APTR[Abase + (size_t)(h)*4096 + (size_t)(aq + q_)*512]; \
      BH[q_] = *(const f16x8*)&BPTR[Bbase + (size_t)(h)*4096 + (size_t)(bq + q_)*512]; \
    } \
  } while(0)

#define MFMA16(AH, BH) do { \
    __builtin_amdgcn_s_setprio(1); \
    _Pragma("unroll") \
    for (int mi_ = 0; mi_ < 4; ++mi_) \
      _Pragma("unroll") \
      for (int ni_ = 0; ni_ < 4; ++ni_) \
        acc[mi_][ni_] = __builtin_amdgcn_mfma_f32_16x16x32_f16(AH[mi_], BH[ni_], acc[mi_][ni_], 0,0,0); \
    __builtin_amdgcn_s_setprio(0); \
  } while(0)

// ---------------- K3 (fused): blocks 0..575 = sim -> Mbits+Bbits; 576..1087 = gemm_ht ----------------
// __launch_bounds__(256, 3): VGPR cap ~168 so BOTH register-prefetch buffer sets stay live (r22-proven).
__global__ __launch_bounds__(256, 3) void k_sim_ht(const _Float16* __restrict__ yf,
                                                   const _Float16* __restrict__ Wf,
                                                   const float* __restrict__ rnorm,
                                                   uint16_t* __restrict__ Mbits,
                                                   uint16_t* __restrict__ Bbits,
                                                   _Float16* __restrict__ htf) {
  __shared__ __align__(16) _Float16 sbuf[16384];   // used only by ht path (output staging)
  int bid0 = blockIdx.x;
  int tid = threadIdx.x, wid = tid>>6, lane = tid&63;
  int wm = (wid>>1)*64, wn = (wid&1)*64;
  int aq = (wm>>4), bq = (wn>>4);
  if (bid0 < 576) {
    // ---- sim path: zero-LDS with register double-buffer prefetch ----
    int swz = (bid0 & 7)*72 + (bid0 >> 3);      // bijective: 576 = 8*72
    int b = swz / 36, p = swz - b*36;
    int ti = 0;
    while ((ti+1)*(ti+2)/2 <= p) ++ti;
    int tj = p - ti*(ti+1)/2;                   // tj <= ti
    size_t Abase = ((size_t)(b*8+ti))*65536 + (size_t)lane*8;
    size_t Bbase = ((size_t)(b*8+tj))*65536 + (size_t)lane*8;
    f32x4 acc[4][4] = {};
    f16x8 A0[4], B0[4], A1[4], B1[4];
    FRAG_LD(A0, B0, yf, yf, 0);
    for (int hp = 0; hp < 8; ++hp) {
      FRAG_LD(A1, B1, yf, yf, 2*hp+1);
      MFMA16(A0, B0);
      if (hp < 7) FRAG_LD(A0, B0, yf, yf, 2*hp+2);
      MFMA16(A1, B1);
    }
    int hi = lane>>4, colL = lane&15;
    #pragma unroll
    for (int mi = 0; mi < 4; ++mi) {
      #pragma unroll
      for (int r2 = 0; r2 < 4; ++r2) {
        int t_g = ti*128 + wm + mi*16 + hi*4 + r2;
        int git = b*NS + t_g;
        #pragma unroll
        for (int ni = 0; ni < 4; ++ni) {
          int s_g = tj*128 + wn + ni*16 + colL;
          float sim = acc[mi][ni][r2];
          bool bit  = (s_g == t_g) || (s_g < t_g && sim > 0.9f);
          bool cond = (s_g < t_g) && (fabsf(sim - 0.9f) <= SIM_BAND);
          unsigned long long bal = __ballot(bit);
          unsigned long long bb  = __ballot(cond);
          if (colL == 0) {
            int widx = (tj*128 + wn + ni*16)>>4;
            Mbits[(size_t)git*64 + widx] = (uint16_t)((bal >> (hi*16)) & 0xFFFFull);
            Bbits[(size_t)git*64 + widx] = (uint16_t)((bb  >> (hi*16)) & 0xFFFFull);
          }
        }
      }
    }
  } else {
    // ---- gemm_ht path: zero-LDS + register prefetch; LDS only for coalesced output ----
    int bidh = bid0 - 576;
    int swz = (bidh&7)*64 + (bidh>>3);          // bijective: 512 = 8*64
    int mt = swz&3, it = swz>>2;
    int b = it>>3, tblk = it&7;
    size_t Abase = ((size_t)mt)*65536 + (size_t)lane*8;
    size_t Bbase = ((size_t)(b*8+tblk))*65536 + (size_t)lane*8;
    f32x4 acc[4][4] = {};
    f16x8 A0[4], B0[4], A1[4], B1[4];
    FRAG_LD(A0, B0, Wf, yf, 0);
    for (int hp = 0; hp < 8; ++hp) {
      FRAG_LD(A1, B1, Wf, yf, 2*hp+1);
      MFMA16(A0, B0);
      if (hp < 7) FRAG_LD(A0, B0, Wf, yf, 2*hp+2);
      MFMA16(A1, B1);
    }
    {
      int rbase = (lane>>4)*4, colL = lane&15;
      #pragma unroll
      for (int ni = 0; ni < 4; ++ni) {
        int i_local = wn + ni*16 + colL;
        int gn = it*128 + i_local;
        float xn = 1.0f / rnorm[gn];
        int tsel = i_local>>6, ic = i_local&63;
        int kb = ic>>5, g = (ic>>3)&3, j = ic&7;
        int base = tsel*8192 + (kb*512 + g*16)*8 + j;
        #pragma unroll
        for (int mi = 0; mi < 4; ++mi)
          #pragma unroll
          for (int r2 = 0; r2 < 4; ++r2) {
            int o_local = wm + mi*16 + rbase + r2;
            int m = o_local>>4, r = o_local&15;
            sbuf[base + (m*64 + r)*8] = (_Float16)(acc[mi][ni][r2] * xn);
          }
      }
    }
    __syncthreads();
    {
      size_t gbase = ((size_t)((mt*NB + b)*16 + tblk*2))*8192;
      const uint4* src = (const uint4*)sbuf;
      uint4* dst = (uint4*)(htf + gbase);
      #pragma unroll
      for (int k = 0; k < 8; ++k) dst[tid + k*256] = src[tid + k*256];
    }
  }
}

// ---------------- K4: masked softmax w/ inline wave-cooperative exact recheck -> Pf ----------------
__global__ __launch_bounds__(256) void k_softmax(const uint32_t* __restrict__ Mw,
                                                 const uint32_t* __restrict__ Bw,
                                                 const float* __restrict__ x,
                                                 const float* __restrict__ rnorm,
                                                 const float* __restrict__ a_src,
                                                 const float* __restrict__ a_dst,
                                                 _Float16* __restrict__ Pf) {
  __shared__ __align__(16) _Float16 pbuf[4][1032];
  int wid = threadIdx.x>>6, lane = threadIdx.x&63;
  int rowid = blockIdx.x*4 + wid;
  int t = rowid & (NS-1), b = rowid >> 10;
  int n = t + 1;
  const float* as = a_src + b*NS;
  float adv = a_dst[rowid];
  uint32_t w = Mw[(size_t)rowid*32 + (lane>>1)];
  uint32_t bits16 = (lane&1) ? (w>>16) : (w & 0xFFFFu);
  uint32_t w2 = Bw[(size_t)rowid*32 + (lane>>1)];
  uint32_t bb16 = (lane&1) ? (w2>>16) : (w2 & 0xFFFFu);
  int s0 = lane*16;
  // CAUSAL GATE: chunks with s >= n were never written by sim (hold ws poison) -> mask them out
  {
    int rem = n - s0;
    uint32_t gmask = (rem <= 0) ? 0u : (rem >= 16 ? 0xFFFFu : ((1u<<rem)-1u));
    bb16 &= gmask;
  }
  float4 a0 = *(const float4*)&as[s0];
  float4 a1 = *(const float4*)&as[s0+4];
  float4 a2 = *(const float4*)&as[s0+8];
  float4 a3 = *(const float4*)&as[s0+12];
  float va[16] = {a0.x,a0.y,a0.z,a0.w, a1.x,a1.y,a1.z,a1.w,
                  a2.x,a2.y,a2.z,a2.w, a3.x,a3.y,a3.z,a3.w};
  float pr[16];
  #pragma unroll
  for (int k = 0; k < 16; ++k) {
    int s = s0 + k;
    bool on = (s < n) && ((bits16>>k)&1);
    float vv = adv + va[k];
    float v = (vv > 0.f) ? vv : 0.2f*vv;
    pr[k] = on ? v : -INFINITY;
  }
  // ---- inline exact recheck (wave-cooperative); decisions collected in bitmasks ----
  uint32_t fix_on = 0u, fix_off = 0u;
  unsigned long long anyb = __ballot(bb16 != 0u);
  if (anyb) {
    float rnt = rnorm[rowid];
    const float* xt = x + (size_t)rowid*ND + lane*8;
    float4 t0v = *(const float4*)xt;
    float4 t1v = *(const float4*)(xt+4);
    while (anyb) {
      int src_lane = __ffsll(anyb) - 1;
      anyb &= anyb - 1ULL;
      unsigned bits = __shfl(bb16, src_lane, 64);
      while (bits) {
        int k = __ffs(bits) - 1;
        bits &= bits - 1u;
        int s = src_lane*16 + k;
        const float* xs = x + ((size_t)(b*NS + s))*ND + lane*8;
        float4 s0v = *(const float4*)xs;
        float4 s1v = *(const float4*)(xs+4);
        float d = 0.f;
        d = fmaf(t0v.x,s0v.x, fmaf(t0v.y,s0v.y, fmaf(t0v.z,s0v.z, fmaf(t0v.w,s0v.w, d))));
        d = fmaf(t1v.x,s1v.x, fmaf(t1v.y,s1v.y, fmaf(t1v.z,s1v.z, fmaf(t1v.w,s1v.w, d))));
        #pragma unroll
        for (int off = 32; off > 0; off >>= 1) d += __shfl_xor(d, off, 64);
        float sim = d * rnt * rnorm[b*NS+s];
        bool on2 = sim > 0.9f;
        if (lane == src_lane) {
          if (on2) fix_on  |= (1u<<k);
          else     fix_off |= (1u<<k);
        }
      }
    }
  }
  #pragma unroll
  for (int k = 0; k < 16; ++k) {
    float vv = adv + va[k];
    float v = (vv > 0.f) ? vv : 0.2f*vv;
    if ((fix_on >>k)&1) pr[k] = v;
    if ((fix_off>>k)&1) pr[k] = -INFINITY;
  }
  // ---- reduction + normalize + frag-order store ----
  float lm = -INFINITY;
  #pragma unroll
  for (int k = 0; k < 16; ++k) lm = fmaxf(lm, pr[k]);
  #pragma unroll
  for (int off = 32; off > 0; off >>= 1) lm = fmaxf(lm, __shfl_xor(lm, off, 64));
  float ls = 0.f;
  #pragma unroll
  for (int k = 0; k < 16; ++k) { pr[k] = __expf(pr[k] - lm); ls += pr[k]; }
  #pragma unroll
  for (int off = 32; off > 0; off >>= 1) ls += __shfl_xor(ls, off, 64);
  float inv = 1.0f / ls;
  union { _Float16 hh[8]; uint4 u; } pk0, pk1;
  #pragma unroll
  for (int j = 0; j < 8; ++j) pk0.hh[j] = (_Float16)(pr[j]*inv);
  #pragma unroll
  for (int j = 0; j < 8; ++j) pk1.hh[j] = (_Float16)(pr[8+j]*inv);
  *(uint4*)&pbuf[wid][s0]   = pk0.u;
  *(uint4*)&pbuf[wid][s0+8] = pk1.u;
  __syncthreads();
  int t0 = (blockIdx.x*4) & (NS-1);
  int b0 = (blockIdx.x*4) >> 10;
  int end = ((t0 >> 7) + 1) << 7;
  int m = (t0>>4)&7, r0 = t0&15;
  size_t tbase = ((size_t)(b0*8 + (t0>>7)))*131072;
  int nslots = (end>>3)*4;
  for (int u = threadIdx.x; u < nslots; u += 256) {
    int rr = u&3, c8 = u>>2;
    int icol = c8*8;
    int k0c = icol>>6, kb = (icol>>5)&1, g = (icol>>3)&3;
    uint4 v = *(const uint4*)&pbuf[rr][icol];
    *(uint4*)&Pf[tbase + (size_t)k0c*8192 + (size_t)(kb*512 + m*64 + g*16 + r0 + rr)*8] = v;
  }
}

// ---------------- K5: out = relu(P @ h + bias) -- zero-LDS + register prefetch, causal ----------------
__global__ __launch_bounds__(256, 3) void k_pv(const _Float16* __restrict__ Pf,
                                               const _Float16* __restrict__ htf,
                                               const float* __restrict__ bias,
                                               float* __restrict__ out) {
  int bid = blockIdx.x;
  int swz = (bid&7)*64 + (bid>>3);          // bijective: 512 = 8*64
  int b = swz>>5, rem = swz&31, mt = rem>>2, nt = rem&3;
  int tid = threadIdx.x, wid = tid>>6, lane = tid&63;
  int wm = (wid>>1)*64, wn = (wid&1)*64;
  size_t Abase = ((size_t)((b*8 + mt)*16))*8192 + (size_t)lane*8;
  size_t Bbase = ((size_t)((nt*NB + b)*16))*8192 + (size_t)lane*8;
  int aq = (wm>>4), bq = (wn>>4);
  f32x4 acc[4][4] = {};
  int nhp = 2*(mt+1);
  f16x8 A0[4], B0[4], A1[4], B1[4];
  FRAG_LD(A0, B0, Pf, htf, 0);
  for (int hp = 0; hp < nhp; ++hp) {
    FRAG_LD(A1, B1, Pf, htf, 2*hp+1);
    MFMA16(A0, B0);
    if (hp < nhp-1) FRAG_LD(A0, B0, Pf, htf, 2*hp+2);
    MFMA16(A1, B1);
  }
  int m0 = mt*128, n0 = nt*128;
  int rbase = (lane>>4)*4, col = lane&15;
  #pragma unroll
  for (int mi = 0; mi < 4; ++mi)
    #pragma unroll
    for (int ni = 0; ni < 4; ++ni) {
      int gm = m0 + wm + mi*16 + rbase;
      int gn = n0 + wn + ni*16 + col;
      float bv = bias[gn];
      #pragma unroll
      for (int r2 = 0; r2 < 4; ++r2)
        out[((size_t)b*NS + gm + r2)*NO + gn] = fmaxf(acc[mi][ni][r2] + bv, 0.0f);
    }
}

extern "C" void kernel_launch(void* const* d_in, const int* in_sizes, int n_in,
                              void* d_out, int out_size, void* d_ws, size_t ws_size,
                              hipStream_t stream) {
  (void)in_sizes; (void)n_in; (void)out_size; (void)ws_size;
  const float* x       = (const float*)d_in[0];
  const float* W       = (const float*)d_in[1];
  const float* att_src = (const float*)d_in[2];
  const float* att_dst = (const float*)d_in[3];
  const float* bias    = (const float*)d_in[4];
  float* out = (float*)d_out;

  char* ws = (char*)d_ws;
  _Float16*     yf    = (_Float16*)    (ws + 0);           // 16 MB [prep_y..sim_ht]
  _Float16*     htf   = (_Float16*)    (ws + 16777216);    // 16 MB [sim_ht..pv]
  _Float16*     Pf    = (_Float16*)    (ws + 33554432);    // 32 MB [softmax..pv]
  uint16_t*     Mbits = (uint16_t*)    (ws + 67108864);    //  2 MB [sim_ht..softmax]
  uint16_t*     Bbits = (uint16_t*)    (ws + 69206016);    //  2 MB [sim_ht..softmax]
  _Float16*     Wf    = (_Float16*)    (ws + 71303168);    // 512 KB [prep_w2..sim_ht]
  float*        watt_s= (float*)       (ws + 71827456);    //  2 KB
  float*        watt_d= (float*)       (ws + 71829504);    //  2 KB
  float*        rnorm = (float*)       (ws + 71831552);    // 64 KB
  float*        a_src = (float*)       (ws + 71897088);    // 64 KB
  float*        a_dst = (float*)       (ws + 71962624);    // 64 KB

  k_prep_w2<<<dim3(34),   dim3(256), 0, stream>>>(W, att_src, att_dst, Wf, watt_s, watt_d);
  k_prep_y <<<dim3(256),  dim3(256), 0, stream>>>(x, yf, rnorm, a_src, a_dst, watt_s, watt_d);
  k_sim_ht <<<dim3(1088), dim3(256), 0, stream>>>(yf, Wf, rnorm, Mbits, Bbits, htf);
  k_softmax<<<dim3(4096), dim3(256), 0, stream>>>((const uint32_t*)Mbits, (const uint32_t*)Bbits,
                                                  x, rnorm, a_src, a_dst, Pf);
  k_pv     <<<dim3(512),  dim3(256), 0, stream>>>(Pf, htf, bias, out);
}

// Round 26
// 99.957 us; speedup vs baseline: 1.0643x; 1.0020x over previous
//
#include <hip/hip_runtime.h>
#include <hip/hip_bf16.h>
#include <stdint.h>

#define NB 16
#define NS 1024
#define ND 512
#define NO 512
#define NROW (NB*NS)   // 16384
#define SIM_BAND 1.5e-3f

typedef float f32x4 __attribute__((ext_vector_type(4)));
typedef _Float16 f16x8 __attribute__((ext_vector_type(8)));

// ---------------- K1: merged W-prep: blocks 0..31 = Wf frag tiles (f16), 32..33 = watt ----------------
__global__ __launch_bounds__(256) void k_prep_w2(const float* __restrict__ W,
                                                 const float* __restrict__ att_src,
                                                 const float* __restrict__ att_dst,
                                                 _Float16* __restrict__ Wf,
                                                 float* __restrict__ watt_s,
                                                 float* __restrict__ watt_d) {
  __shared__ float as_[512], ad_[512];
  int blk = blockIdx.x, tid = threadIdx.x;
  if (blk < 32) {
    int mt = blk>>3, k0c = blk&7;
    size_t base = ((size_t)(mt*8 + k0c))*8192;
    #pragma unroll
    for (int pp = 0; pp < 4; ++pp) {
      int id = pp*256 + tid;
      int kb = id>>9, m = (id>>6)&7, g = (id>>4)&3, r = id&15;
      int o = mt*128 + m*16 + r;
      int d0 = k0c*64 + kb*32 + g*8;
      union { _Float16 h[8]; uint4 u; } pk;
      #pragma unroll
      for (int j = 0; j < 8; ++j) pk.h[j] = (_Float16)W[(size_t)(d0+j)*NO + o];
      *(uint4*)&Wf[base + id*8] = pk.u;
    }
  } else {
    as_[tid] = att_src[tid]; as_[tid+256] = att_src[tid+256];
    ad_[tid] = att_dst[tid]; ad_[tid+256] = att_dst[tid+256];
    __syncthreads();
    int d = (blk-32)*256 + tid;
    const float* wr = W + (size_t)d*NO;
    float s = 0.f, dd = 0.f;
    for (int o = 0; o < NO; o += 4) {
      float4 w = *(const float4*)&wr[o];
      s  = fmaf(w.x, as_[o], fmaf(w.y, as_[o+1], fmaf(w.z, as_[o+2], fmaf(w.w, as_[o+3], s))));
      dd = fmaf(w.x, ad_[o], fmaf(w.y, ad_[o+1], fmaf(w.z, ad_[o+2], fmaf(w.w, ad_[o+3], dd))));
    }
    watt_s[d] = s;
    watt_d[d] = dd;
  }
}

// ---------------- K2: rnorm + a_src/a_dst (via watt) + yf = f16(x*rn) fragment-order ----------------
__global__ __launch_bounds__(256) void k_prep_y(const float* __restrict__ x,
                                                _Float16* __restrict__ yf,
                                                float* __restrict__ rnorm,
                                                float* __restrict__ a_src,
                                                float* __restrict__ a_dst,
                                                const float* __restrict__ watt_s,
                                                const float* __restrict__ watt_d) {
  __shared__ float ws_[512], wd_[512];
  int tid = threadIdx.x, blk = blockIdx.x;
  ws_[tid] = watt_s[tid]; ws_[tid+256] = watt_s[tid+256];
  wd_[tid] = watt_d[tid]; wd_[tid+256] = watt_d[tid+256];
  __syncthreads();
  int r = tid>>2, q = tid&3;
  int grow = blk*64 + r;
  const float* xr = x + (size_t)grow*ND + q*128;
  float ssq = 0.f, as = 0.f, ad = 0.f;
  #pragma unroll
  for (int c8 = 0; c8 < 16; ++c8) {
    float4 v0 = *(const float4*)&xr[c8*8];
    float4 v1 = *(const float4*)&xr[c8*8+4];
    float vv[8] = {v0.x,v0.y,v0.z,v0.w,v1.x,v1.y,v1.z,v1.w};
    #pragma unroll
    for (int j = 0; j < 8; ++j) {
      int c = q*128 + c8*8 + j;
      ssq = fmaf(vv[j], vv[j], ssq);
      as  = fmaf(vv[j], ws_[c], as);
      ad  = fmaf(vv[j], wd_[c], ad);
    }
  }
  ssq += __shfl_xor(ssq, 1, 64); ssq += __shfl_xor(ssq, 2, 64);
  as  += __shfl_xor(as, 1, 64);  as  += __shfl_xor(as, 2, 64);
  ad  += __shfl_xor(ad, 1, 64);  ad  += __shfl_xor(ad, 2, 64);
  float rn = 1.0f / fmaxf(sqrtf(ssq), 1e-12f);
  if (q == 0) { rnorm[grow] = rn; a_src[grow] = as; a_dst[grow] = ad; }
  int trow = grow & (NS-1), b = grow >> 10;
  int m = (trow>>4)&7, rr = trow&15;
  size_t tilebase = ((size_t)(b*8 + (trow>>7)))*65536;
  #pragma unroll
  for (int c8 = 0; c8 < 16; ++c8) {
    int col = q*128 + c8*8;
    int k0c = col>>6, cc = col&63, kb = cc>>5, g = (cc>>3)&3;
    int id = kb*512 + m*64 + g*16 + rr;
    size_t off = tilebase + (size_t)k0c*8192 + id*8;
    float4 v0 = *(const float4*)&xr[c8*8];
    float4 v1 = *(const float4*)&xr[c8*8+4];
    float vv[8] = {v0.x,v0.y,v0.z,v0.w,v1.x,v1.y,v1.z,v1.w};
    union { _Float16 h[8]; uint4 u; } pk;
    #pragma unroll
    for (int j = 0; j < 8; ++j) pk.h[j] = (_Float16)(vv[j]*rn);   // RTN f16
    *(uint4*)&yf[off] = pk.u;
  }
}

// ---- zero-LDS fragment load (half h covers 32 k-cols): frag = base + h*4096 + q*512 ----
#define FRAG_LD(AH, BH, APTR, BPTR, h) do { \
    _Pragma("unroll") \
    for (int q_ = 0; q_ < 4; ++q_) { \
      AH[q_] = *(const f16x8*)&APTR[Abase + (size_t)(h)*4096 + (size_t)(aq + q_)*512]; \
      BH[q_] = *(const f16x8*)&BPTR[Bbase + (size_t)(h)*4096 + (size_t)(bq + q_)*512]; \
    } \
  } while(0)

#define MFMA16(AH, BH) do { \
    __builtin_amdgcn_s_setprio(1); \
    _Pragma("unroll") \
    for (int mi_ = 0; mi_ < 4; ++mi_) \
      _Pragma("unroll") \
      for (int ni_ = 0; ni_ < 4; ++ni_) \
        acc[mi_][ni_] = __builtin_amdgcn_mfma_f32_16x16x32_f16(AH[mi_], BH[ni_], acc[mi_][ni_], 0,0,0); \
    __builtin_amdgcn_s_setprio(0); \
  } while(0)

// ---------------- K3 (fused): blocks 0..575 = sim -> Mbits+Bbits; 576..1087 = gemm_ht ----------------
// __launch_bounds__(256, 3): VGPR cap ~168 so BOTH register-prefetch buffer sets stay live (r22-proven).
__global__ __launch_bounds__(256, 3) void k_sim_ht(const _Float16* __restrict__ yf,
                                                   const _Float16* __restrict__ Wf,
                                                   const float* __restrict__ rnorm,
                                                   uint16_t* __restrict__ Mbits,
                                                   uint16_t* __restrict__ Bbits,
                                                   _Float16* __restrict__ htf) {
  __shared__ __align__(16) _Float16 sbuf[16384];   // used only by ht path (output staging)
  int bid0 = blockIdx.x;
  int tid = threadIdx.x, wid = tid>>6, lane = tid&63;
  int wm = (wid>>1)*64, wn = (wid&1)*64;
  int aq = (wm>>4), bq = (wn>>4);
  if (bid0 < 576) {
    // ---- sim path: zero-LDS with register double-buffer prefetch ----
    int swz = (bid0 & 7)*72 + (bid0 >> 3);      // bijective: 576 = 8*72
    int b = swz / 36, p = swz - b*36;
    int ti = 0;
    while ((ti+1)*(ti+2)/2 <= p) ++ti;
    int tj = p - ti*(ti+1)/2;                   // tj <= ti
    size_t Abase = ((size_t)(b*8+ti))*65536 + (size_t)lane*8;
    size_t Bbase = ((size_t)(b*8+tj))*65536 + (size_t)lane*8;
    f32x4 acc[4][4] = {};
    f16x8 A0[4], B0[4], A1[4], B1[4];
    FRAG_LD(A0, B0, yf, yf, 0);
    for (int hp = 0; hp < 8; ++hp) {
      FRAG_LD(A1, B1, yf, yf, 2*hp+1);
      MFMA16(A0, B0);
      if (hp < 7) FRAG_LD(A0, B0, yf, yf, 2*hp+2);
      MFMA16(A1, B1);
    }
    int hi = lane>>4, colL = lane&15;
    #pragma unroll
    for (int mi = 0; mi < 4; ++mi) {
      #pragma unroll
      for (int r2 = 0; r2 < 4; ++r2) {
        int t_g = ti*128 + wm + mi*16 + hi*4 + r2;
        int git = b*NS + t_g;
        #pragma unroll
        for (int ni = 0; ni < 4; ++ni) {
          int s_g = tj*128 + wn + ni*16 + colL;
          float sim = acc[mi][ni][r2];
          bool bit  = (s_g == t_g) || (s_g < t_g && sim > 0.9f);
          bool cond = (s_g < t_g) && (fabsf(sim - 0.9f) <= SIM_BAND);
          unsigned long long bal = __ballot(bit);
          unsigned long long bb  = __ballot(cond);
          if (colL == 0) {
            int widx = (tj*128 + wn + ni*16)>>4;
            Mbits[(size_t)git*64 + widx] = (uint16_t)((bal >> (hi*16)) & 0xFFFFull);
            Bbits[(size_t)git*64 + widx] = (uint16_t)((bb  >> (hi*16)) & 0xFFFFull);
          }
        }
      }
    }
  } else {
    // ---- gemm_ht path: zero-LDS + register prefetch; LDS only for coalesced output ----
    int bidh = bid0 - 576;
    int swz = (bidh&7)*64 + (bidh>>3);          // bijective: 512 = 8*64
    int mt = swz&3, it = swz>>2;
    int b = it>>3, tblk = it&7;
    size_t Abase = ((size_t)mt)*65536 + (size_t)lane*8;
    size_t Bbase = ((size_t)(b*8+tblk))*65536 + (size_t)lane*8;
    f32x4 acc[4][4] = {};
    f16x8 A0[4], B0[4], A1[4], B1[4];
    FRAG_LD(A0, B0, Wf, yf, 0);
    for (int hp = 0; hp < 8; ++hp) {
      FRAG_LD(A1, B1, Wf, yf, 2*hp+1);
      MFMA16(A0, B0);
      if (hp < 7) FRAG_LD(A0, B0, Wf, yf, 2*hp+2);
      MFMA16(A1, B1);
    }
    {
      int rbase = (lane>>4)*4, colL = lane&15;
      #pragma unroll
      for (int ni = 0; ni < 4; ++ni) {
        int i_local = wn + ni*16 + colL;
        int gn = it*128 + i_local;
        float xn = 1.0f / rnorm[gn];
        int tsel = i_local>>6, ic = i_local&63;
        int kb = ic>>5, g = (ic>>3)&3, j = ic&7;
        int base = tsel*8192 + (kb*512 + g*16)*8 + j;
        #pragma unroll
        for (int mi = 0; mi < 4; ++mi)
          #pragma unroll
          for (int r2 = 0; r2 < 4; ++r2) {
            int o_local = wm + mi*16 + rbase + r2;
            int m = o_local>>4, r = o_local&15;
            sbuf[base + (m*64 + r)*8] = (_Float16)(acc[mi][ni][r2] * xn);
          }
      }
    }
    __syncthreads();
    {
      size_t gbase = ((size_t)((mt*NB + b)*16 + tblk*2))*8192;
      const uint4* src = (const uint4*)sbuf;
      uint4* dst = (uint4*)(htf + gbase);
      #pragma unroll
      for (int k = 0; k < 8; ++k) dst[tid + k*256] = src[tid + k*256];
    }
  }
}

// ---------------- K4: masked softmax w/ inline wave-cooperative exact recheck -> Pf ----------------
__global__ __launch_bounds__(256) void k_softmax(const uint32_t* __restrict__ Mw,
                                                 const uint32_t* __restrict__ Bw,
                                                 const float* __restrict__ x,
                                                 const float* __restrict__ rnorm,
                                                 const float* __restrict__ a_src,
                                                 const float* __restrict__ a_dst,
                                                 _Float16* __restrict__ Pf) {
  __shared__ __align__(16) _Float16 pbuf[4][1032];
  int wid = threadIdx.x>>6, lane = threadIdx.x&63;
  int rowid = blockIdx.x*4 + wid;
  int t = rowid & (NS-1), b = rowid >> 10;
  int n = t + 1;
  const float* as = a_src + b*NS;
  float adv = a_dst[rowid];
  uint32_t w = Mw[(size_t)rowid*32 + (lane>>1)];
  uint32_t bits16 = (lane&1) ? (w>>16) : (w & 0xFFFFu);
  uint32_t w2 = Bw[(size_t)rowid*32 + (lane>>1)];
  uint32_t bb16 = (lane&1) ? (w2>>16) : (w2 & 0xFFFFu);
  int s0 = lane*16;
  // CAUSAL GATE: chunks with s >= n were never written by sim (hold ws poison) -> mask them out
  {
    int rem = n - s0;
    uint32_t gmask = (rem <= 0) ? 0u : (rem >= 16 ? 0xFFFFu : ((1u<<rem)-1u));
    bb16 &= gmask;
  }
  float4 a0 = *(const float4*)&as[s0];
  float4 a1 = *(const float4*)&as[s0+4];
  float4 a2 = *(const float4*)&as[s0+8];
  float4 a3 = *(const float4*)&as[s0+12];
  float va[16] = {a0.x,a0.y,a0.z,a0.w, a1.x,a1.y,a1.z,a1.w,
                  a2.x,a2.y,a2.z,a2.w, a3.x,a3.y,a3.z,a3.w};
  float pr[16];
  #pragma unroll
  for (int k = 0; k < 16; ++k) {
    int s = s0 + k;
    bool on = (s < n) && ((bits16>>k)&1);
    float vv = adv + va[k];
    float v = (vv > 0.f) ? vv : 0.2f*vv;
    pr[k] = on ? v : -INFINITY;
  }
  // ---- inline exact recheck (wave-cooperative); decisions collected in bitmasks ----
  uint32_t fix_on = 0u, fix_off = 0u;
  unsigned long long anyb = __ballot(bb16 != 0u);
  if (anyb) {
    float rnt = rnorm[rowid];
    const float* xt = x + (size_t)rowid*ND + lane*8;
    float4 t0v = *(const float4*)xt;
    float4 t1v = *(const float4*)(xt+4);
    while (anyb) {
      int src_lane = __ffsll(anyb) - 1;
      anyb &= anyb - 1ULL;
      unsigned bits = __shfl(bb16, src_lane, 64);
      while (bits) {
        int k = __ffs(bits) - 1;
        bits &= bits - 1u;
        int s = src_lane*16 + k;
        const float* xs = x + ((size_t)(b*NS + s))*ND + lane*8;
        float4 s0v = *(const float4*)xs;
        float4 s1v = *(const float4*)(xs+4);
        float d = 0.f;
        d = fmaf(t0v.x,s0v.x, fmaf(t0v.y,s0v.y, fmaf(t0v.z,s0v.z, fmaf(t0v.w,s0v.w, d))));
        d = fmaf(t1v.x,s1v.x, fmaf(t1v.y,s1v.y, fmaf(t1v.z,s1v.z, fmaf(t1v.w,s1v.w, d))));
        #pragma unroll
        for (int off = 32; off > 0; off >>= 1) d += __shfl_xor(d, off, 64);
        float sim = d * rnt * rnorm[b*NS+s];
        bool on2 = sim > 0.9f;
        if (lane == src_lane) {
          if (on2) fix_on  |= (1u<<k);
          else     fix_off |= (1u<<k);
        }
      }
    }
  }
  #pragma unroll
  for (int k = 0; k < 16; ++k) {
    float vv = adv + va[k];
    float v = (vv > 0.f) ? vv : 0.2f*vv;
    if ((fix_on >>k)&1) pr[k] = v;
    if ((fix_off>>k)&1) pr[k] = -INFINITY;
  }
  // ---- reduction + normalize + frag-order store ----
  float lm = -INFINITY;
  #pragma unroll
  for (int k = 0; k < 16; ++k) lm = fmaxf(lm, pr[k]);
  #pragma unroll
  for (int off = 32; off > 0; off >>= 1) lm = fmaxf(lm, __shfl_xor(lm, off, 64));
  float ls = 0.f;
  #pragma unroll
  for (int k = 0; k < 16; ++k) { pr[k] = __expf(pr[k] - lm); ls += pr[k]; }
  #pragma unroll
  for (int off = 32; off > 0; off >>= 1) ls += __shfl_xor(ls, off, 64);
  float inv = 1.0f / ls;
  union { _Float16 hh[8]; uint4 u; } pk0, pk1;
  #pragma unroll
  for (int j = 0; j < 8; ++j) pk0.hh[j] = (_Float16)(pr[j]*inv);
  #pragma unroll
  for (int j = 0; j < 8; ++j) pk1.hh[j] = (_Float16)(pr[8+j]*inv);
  *(uint4*)&pbuf[wid][s0]   = pk0.u;
  *(uint4*)&pbuf[wid][s0+8] = pk1.u;
  __syncthreads();
  int t0 = (blockIdx.x*4) & (NS-1);
  int b0 = (blockIdx.x*4) >> 10;
  int end = ((t0 >> 7) + 1) << 7;
  int m = (t0>>4)&7, r0 = t0&15;
  size_t tbase = ((size_t)(b0*8 + (t0>>7)))*131072;
  int nslots = (end>>3)*4;
  for (int u = threadIdx.x; u < nslots; u += 256) {
    int rr = u&3, c8 = u>>2;
    int icol = c8*8;
    int k0c = icol>>6, kb = (icol>>5)&1, g = (icol>>3)&3;
    uint4 v = *(const uint4*)&pbuf[rr][icol];
    *(uint4*)&Pf[tbase + (size_t)k0c*8192 + (size_t)(kb*512 + m*64 + g*16 + r0 + rr)*8] = v;
  }
}

// ---------------- K5: out = relu(P @ h + bias) -- zero-LDS + register prefetch, causal ----------------
__global__ __launch_bounds__(256, 3) void k_pv(const _Float16* __restrict__ Pf,
                                               const _Float16* __restrict__ htf,
                                               const float* __restrict__ bias,
                                               float* __restrict__ out) {
  int bid = blockIdx.x;
  int swz = (bid&7)*64 + (bid>>3);          // bijective: 512 = 8*64
  int b = swz>>5, rem = swz&31, mt = rem>>2, nt = rem&3;
  int tid = threadIdx.x, wid = tid>>6, lane = tid&63;
  int wm = (wid>>1)*64, wn = (wid&1)*64;
  size_t Abase = ((size_t)((b*8 + mt)*16))*8192 + (size_t)lane*8;
  size_t Bbase = ((size_t)((nt*NB + b)*16))*8192 + (size_t)lane*8;
  int aq = (wm>>4), bq = (wn>>4);
  f32x4 acc[4][4] = {};
  int nhp = 2*(mt+1);
  f16x8 A0[4], B0[4], A1[4], B1[4];
  FRAG_LD(A0, B0, Pf, htf, 0);
  for (int hp = 0; hp < nhp; ++hp) {
    FRAG_LD(A1, B1, Pf, htf, 2*hp+1);
    MFMA16(A0, B0);
    if (hp < nhp-1) FRAG_LD(A0, B0, Pf, htf, 2*hp+2);
    MFMA16(A1, B1);
  }
  int m0 = mt*128, n0 = nt*128;
  int rbase = (lane>>4)*4, col = lane&15;
  #pragma unroll
  for (int mi = 0; mi < 4; ++mi)
    #pragma unroll
    for (int ni = 0; ni < 4; ++ni) {
      int gm = m0 + wm + mi*16 + rbase;
      int gn = n0 + wn + ni*16 + col;
      float bv = bias[gn];
      #pragma unroll
      for (int r2 = 0; r2 < 4; ++r2)
        out[((size_t)b*NS + gm + r2)*NO + gn] = fmaxf(acc[mi][ni][r2] + bv, 0.0f);
    }
}

extern "C" void kernel_launch(void* const* d_in, const int* in_sizes, int n_in,
                              void* d_out, int out_size, void* d_ws, size_t ws_size,
                              hipStream_t stream) {
  (void)in_sizes; (void)n_in; (void)out_size; (void)ws_size;
  const float* x       = (const float*)d_in[0];
  const float* W       = (const float*)d_in[1];
  const float* att_src = (const float*)d_in[2];
  const float* att_dst = (const float*)d_in[3];
  const float* bias    = (const float*)d_in[4];
  float* out = (float*)d_out;

  char* ws = (char*)d_ws;
  _Float16*     yf    = (_Float16*)    (ws + 0);           // 16 MB [prep_y..sim_ht]
  _Float16*     htf   = (_Float16*)    (ws + 16777216);    // 16 MB [sim_ht..pv]
  _Float16*     Pf    = (_Float16*)    (ws + 33554432);    // 32 MB [softmax..pv]
  uint16_t*     Mbits = (uint16_t*)    (ws + 67108864);    //  2 MB [sim_ht..softmax]
  uint16_t*     Bbits = (uint16_t*)    (ws + 69206016);    //  2 MB [sim_ht..softmax]
  _Float16*     Wf    = (_Float16*)    (ws + 71303168);    // 512 KB [prep_w2..sim_ht]
  float*        watt_s= (float*)       (ws + 71827456);    //  2 KB
  float*        watt_d= (float*)       (ws + 71829504);    //  2 KB
  float*        rnorm = (float*)       (ws + 71831552);    // 64 KB
  float*        a_src = (float*)       (ws + 71897088);    // 64 KB
  float*        a_dst = (float*)       (ws + 71962624);    // 64 KB

  k_prep_w2<<<dim3(34),   dim3(256), 0, stream>>>(W, att_src, att_dst, Wf, watt_s, watt_d);
  k_prep_y <<<dim3(256),  dim3(256), 0, stream>>>(x, yf, rnorm, a_src, a_dst, watt_s, watt_d);
  k_sim_ht <<<dim3(1088), dim3(256), 0, stream>>>(yf, Wf, rnorm, Mbits, Bbits, htf);
  k_softmax<<<dim3(4096), dim3(256), 0, stream>>>((const uint32_t*)Mbits, (const uint32_t*)Bbits,
                                                  x, rnorm, a_src, a_dst, Pf);
  k_pv     <<<dim3(512),  dim3(256), 0, stream>>>(Pf, htf, bias, out);
}